// Round 4
// baseline (179.586 us; speedup 1.0000x reference)
//
#include <hip/hip_runtime.h>

// out[b,i,j,d] = sum_{k<c} A[b,i,k,d] * B[b,k,j,d]   for i,j < c, else 0
// A: (256,64,64,32) f32, strides: b:131072, i:2048, k:32, d:1
// B: (256,64,64,32) f32, strides: b:131072, k:2048, j:32, d:1
//
// v4: v2 geometry (512 thr, 8 blocks/batch, i-chunk 8, ic*256+b block order)
// + float4 over d (thread = (j, d-quad): B load = 1KB contiguous/wave,
//   A load = 128B broadcast/wave)
// + explicit 1-deep register prefetch (9 float4 loads for k+1 in flight
//   under k's 32 FMAs) to attack the latency-bound regime (VALUBusy 7-13%).

#define BATCH 256
#define NN 64
#define ND 32
#define BSTRIDE (NN * NN * ND)   // 131072 floats
#define RSTRIDE (NN * ND)        // 2048 floats
#define R4 (RSTRIDE / 4)         // 512 float4
#define ICHUNK 8

__global__ __launch_bounds__(512, 2) void mp_kernel(
    const float* __restrict__ A,
    const float* __restrict__ B,
    const int* __restrict__ counts,
    float* __restrict__ out)
{
    const int b  = blockIdx.x & (BATCH - 1);
    const int ic = blockIdx.x >> 8;          // 0..7
    const int i0 = ic * ICHUNK;
    const int c  = counts[b];
    const int tid = (int)threadIdx.x;
    const int d4 = tid & 7;                  // d quad: d = 4*d4 .. +3
    const int j  = tid >> 3;                 // 0..63, one j per thread

    const size_t base = (size_t)b * BSTRIDE;
    float* __restrict__ Ob = out + base + (size_t)i0 * RSTRIDE + (size_t)j * ND + d4 * 4;

    // fast path: whole i-chunk invalid -> zero-fill and retire
    if (i0 >= c) {
        const float4 z = make_float4(0.f, 0.f, 0.f, 0.f);
        #pragma unroll
        for (int ii = 0; ii < ICHUNK; ++ii)
            *reinterpret_cast<float4*>(Ob + (size_t)ii * RSTRIDE) = z;
        return;
    }

    const float4* __restrict__ A4 =
        reinterpret_cast<const float4*>(A + base + (size_t)i0 * RSTRIDE) + d4; // + ii*512 + k*8
    const float4* __restrict__ B4 =
        reinterpret_cast<const float4*>(B + base + (size_t)j * ND) + d4;       // + k*512

    float acc[ICHUNK][4];
    #pragma unroll
    for (int ii = 0; ii < ICHUNK; ++ii)
        #pragma unroll
        for (int dd = 0; dd < 4; ++dd)
            acc[ii][dd] = 0.0f;

    // wave w covers j in [8w, 8w+8); skip compute if entirely invalid
    const bool waveActive = (((tid >> 6) << 3) < c);

    if (waveActive) {
        // prime the pipeline: k = 0
        float4 bC = B4[0];
        float4 aC[ICHUNK];
        #pragma unroll
        for (int ii = 0; ii < ICHUNK; ++ii)
            aC[ii] = A4[(size_t)ii * R4];

        #pragma unroll 2
        for (int k = 0; k < c; ++k) {
            // prefetch k+1 (clamped; loads stay in-bounds and independent)
            const int kn = (k + 1 < c) ? (k + 1) : k;
            float4 bN = B4[(size_t)kn * R4];
            float4 aN[ICHUNK];
            #pragma unroll
            for (int ii = 0; ii < ICHUNK; ++ii)
                aN[ii] = A4[(size_t)ii * R4 + (size_t)kn * (ND / 4)];

            #pragma unroll
            for (int ii = 0; ii < ICHUNK; ++ii) {
                acc[ii][0] = fmaf(aC[ii].x, bC.x, acc[ii][0]);
                acc[ii][1] = fmaf(aC[ii].y, bC.y, acc[ii][1]);
                acc[ii][2] = fmaf(aC[ii].z, bC.z, acc[ii][2]);
                acc[ii][3] = fmaf(aC[ii].w, bC.w, acc[ii][3]);
            }

            bC = bN;
            #pragma unroll
            for (int ii = 0; ii < ICHUNK; ++ii)
                aC[ii] = aN[ii];
        }
    }

    // masked store (output poisoned before timing -> write everything)
    const bool jv = (j < c);
    #pragma unroll
    for (int ii = 0; ii < ICHUNK; ++ii) {
        const bool v = jv && ((i0 + ii) < c);
        const float4 o = v ? make_float4(acc[ii][0], acc[ii][1], acc[ii][2], acc[ii][3])
                           : make_float4(0.f, 0.f, 0.f, 0.f);
        *reinterpret_cast<float4*>(Ob + (size_t)ii * RSTRIDE) = o;
    }
}

extern "C" void kernel_launch(void* const* d_in, const int* in_sizes, int n_in,
                              void* d_out, int out_size, void* d_ws, size_t ws_size,
                              hipStream_t stream)
{
    const float* A      = (const float*)d_in[0];
    const float* B      = (const float*)d_in[1];
    const int*   counts = (const int*)d_in[2];
    float* out = (float*)d_out;

    mp_kernel<<<dim3(BATCH * (NN / ICHUNK)), dim3(512), 0, stream>>>(A, B, counts, out);
}

// Round 5
// 97.362 us; speedup vs baseline: 1.8445x; 1.8445x over previous
//
#include <hip/hip_runtime.h>

// out[b,i,j,d] = sum_{k<c} A[b,i,k,d] * B[b,k,j,d]   for i,j < c, else 0
// A: (256,64,64,32) f32, strides: b:131072, i:2048, k:32, d:1
// B: (256,64,64,32) f32, strides: b:131072, k:2048, j:32, d:1
//
// v5: keep v2's inner loop (empirically best: 98us vs 133/179 for float4
// variants) and attack OCCUPANCY/scheduling instead:
//   - prologue kernel partitions the 2048 (b,ic) work items on-device:
//     valid items sorted by c DESCENDING (whales first), zero-fill items last
//   - main kernel reads its (b,ic) from the sorted list in d_ws
// Rationale: VALU work ~8us-equiv, memory floor ~38us, but measured 98us with
// OccupancyPercent=30 and VALUBusy=13 -> latency-bound because instant-retire
// zero blocks churn the dispatcher and whales set a random-start tail.

#define BATCH 256
#define NN 64
#define ND 32
#define BSTRIDE (NN * NN * ND)   // 131072
#define RSTRIDE (NN * ND)        // 2048
#define ICHUNK 8
#define NITEMS (BATCH * (NN / ICHUNK))  // 2048

// ---------------- prologue: partition + counting-sort the work items --------
__global__ __launch_bounds__(512) void mp_prologue(
    const int* __restrict__ counts, int* __restrict__ items)
{
    __shared__ int cLds[BATCH];
    __shared__ int hist[NN + 1];   // keys 0..63 = valid (64-c), 64 = zero-fill
    __shared__ int offs[NN + 1];
    const int tid = (int)threadIdx.x;

    if (tid <= NN) hist[tid] = 0;
    for (int b = tid; b < BATCH; b += 512) cLds[b] = counts[b];
    __syncthreads();

    for (int w = tid; w < NITEMS; w += 512) {
        const int b = w >> 3, ic = w & 7;
        const int c = cLds[b];
        const int key = (ic * ICHUNK < c) ? (NN - c) : NN;
        atomicAdd(&hist[key], 1);
    }
    __syncthreads();

    if (tid == 0) {
        int acc = 0;
        for (int k = 0; k <= NN; ++k) { offs[k] = acc; acc += hist[k]; }
    }
    __syncthreads();

    for (int w = tid; w < NITEMS; w += 512) {
        const int b = w >> 3, ic = w & 7;
        const int c = cLds[b];
        const int key = (ic * ICHUNK < c) ? (NN - c) : NN;
        const int pos = atomicAdd(&offs[key], 1);
        items[pos] = w;
    }
}

// ---------------- main body (v2's proven inner loop) ------------------------
__device__ __forceinline__ void mp_body(
    int b, int ic,
    const float* __restrict__ A, const float* __restrict__ B,
    const int* __restrict__ counts, float* __restrict__ out)
{
    const int i0 = ic << 3;
    const int c  = counts[b];
    const int tid = (int)threadIdx.x;
    const int d  = tid & 31;             // channel
    const int jg = tid >> 5;             // 0..15, group of 4 j's
    const int jb = jg << 2;              // j base

    const size_t base = (size_t)b * BSTRIDE;
    float* __restrict__ Ob = out + base + (size_t)i0 * RSTRIDE + (size_t)jb * ND + d;

    if (i0 >= c) {
        #pragma unroll
        for (int ii = 0; ii < ICHUNK; ++ii)
            #pragma unroll
            for (int jj = 0; jj < 4; ++jj)
                Ob[(size_t)ii * RSTRIDE + jj * ND] = 0.0f;
        return;
    }

    const float* __restrict__ Ai = A + base + (size_t)i0 * RSTRIDE + d;
    const float* __restrict__ Bb = B + base + (size_t)jb * ND + d;

    float acc[ICHUNK][4];
    #pragma unroll
    for (int ii = 0; ii < ICHUNK; ++ii)
        #pragma unroll
        for (int jj = 0; jj < 4; ++jj)
            acc[ii][jj] = 0.0f;

    const bool waveActive = (((tid >> 6) << 3) < c);

    if (waveActive) {
        #pragma unroll 2
        for (int k = 0; k < c; ++k) {
            float av[ICHUNK];
            #pragma unroll
            for (int ii = 0; ii < ICHUNK; ++ii)
                av[ii] = Ai[(size_t)ii * RSTRIDE + k * ND];
            float bv[4];
            #pragma unroll
            for (int jj = 0; jj < 4; ++jj)
                bv[jj] = Bb[(size_t)k * RSTRIDE + jj * ND];
            #pragma unroll
            for (int ii = 0; ii < ICHUNK; ++ii)
                #pragma unroll
                for (int jj = 0; jj < 4; ++jj)
                    acc[ii][jj] = fmaf(av[ii], bv[jj], acc[ii][jj]);
        }
    }

    #pragma unroll
    for (int ii = 0; ii < ICHUNK; ++ii) {
        const bool iv = (i0 + ii) < c;
        #pragma unroll
        for (int jj = 0; jj < 4; ++jj) {
            const bool v = iv && ((jb + jj) < c);
            Ob[(size_t)ii * RSTRIDE + jj * ND] = v ? acc[ii][jj] : 0.0f;
        }
    }
}

__global__ __launch_bounds__(512, 2) void mp_kernel_sorted(
    const float* __restrict__ A, const float* __restrict__ B,
    const int* __restrict__ counts, float* __restrict__ out,
    const int* __restrict__ items)
{
    const int w = items[blockIdx.x];
    mp_body(w >> 3, w & 7, A, B, counts, out);
}

__global__ __launch_bounds__(512, 2) void mp_kernel_direct(
    const float* __restrict__ A, const float* __restrict__ B,
    const int* __restrict__ counts, float* __restrict__ out)
{
    mp_body(blockIdx.x & (BATCH - 1), blockIdx.x >> 8, A, B, counts, out);
}

extern "C" void kernel_launch(void* const* d_in, const int* in_sizes, int n_in,
                              void* d_out, int out_size, void* d_ws, size_t ws_size,
                              hipStream_t stream)
{
    const float* A      = (const float*)d_in[0];
    const float* B      = (const float*)d_in[1];
    const int*   counts = (const int*)d_in[2];
    float* out = (float*)d_out;

    if (ws_size >= NITEMS * sizeof(int)) {
        int* items = (int*)d_ws;
        mp_prologue<<<dim3(1), dim3(512), 0, stream>>>(counts, items);
        mp_kernel_sorted<<<dim3(NITEMS), dim3(512), 0, stream>>>(A, B, counts, out, items);
    } else {
        mp_kernel_direct<<<dim3(NITEMS), dim3(512), 0, stream>>>(A, B, counts, out);
    }
}